// Round 9
// baseline (220.391 us; speedup 1.0000x reference)
//
#include <hip/hip_runtime.h>
#include <hip/hip_bf16.h>
#include <math.h>

// Sizes (fixed): BATCH=2, SEQ=2048, DIM=768, HEADS=8, DK=DV=64, F=192, d_inner=512
// All internal compute in fp16 storage + fp32 MFMA accumulation.

typedef _Float16 f16x8 __attribute__((ext_vector_type(8)));
typedef _Float16 f16x4 __attribute__((ext_vector_type(4)));
typedef float f32x4 __attribute__((ext_vector_type(4)));

#define MFMA16(a, b, c) __builtin_amdgcn_mfma_f32_16x16x32_f16((a), (b), (c), 0, 0, 0)

// async global->LDS, 16B per lane; dest must be (wave-uniform base + lane*16)
#define GL16(gp, lp)                                                       \
  __builtin_amdgcn_global_load_lds(                                        \
      (const __attribute__((address_space(1))) void*)(gp),                 \
      (__attribute__((address_space(3))) void*)(lp), 16, 0, 0)

// 16-lane max-reduce on the VALU pipe (DPP), zero DS-pipe ops.
__device__ __forceinline__ float dpp_fmax16(float x) {
  int v;
  v = __builtin_amdgcn_update_dpp(0, __float_as_int(x), 0xB1, 0xf, 0xf, true);
  x = fmaxf(x, __int_as_float(v));
  v = __builtin_amdgcn_update_dpp(0, __float_as_int(x), 0x4E, 0xf, 0xf, true);
  x = fmaxf(x, __int_as_float(v));
  v = __builtin_amdgcn_update_dpp(0, __float_as_int(x), 0x141, 0xf, 0xf, true);
  x = fmaxf(x, __int_as_float(v));
  v = __builtin_amdgcn_update_dpp(0, __float_as_int(x), 0x140, 0xf, 0xf, true);
  x = fmaxf(x, __int_as_float(v));
  return x;
}

// ---------------- fused prep: x->fp16 | 3 weight transposes | pos embed ----------------
__global__ __launch_bounds__(256) void prep_kernel(
    const float* __restrict__ x, const float* __restrict__ Wq,
    const float* __restrict__ Wk, const float* __restrict__ Wv,
    const float* __restrict__ Wrel, const float* __restrict__ Wo,
    _Float16* __restrict__ xb, _Float16* __restrict__ wqkvt,
    _Float16* __restrict__ wrelt, _Float16* __restrict__ wot,
    _Float16* __restrict__ posb) {
  __shared__ float tile[32][33];
  const int t = threadIdx.x;
  int bid = blockIdx.x;
  if (bid < 3072) {  // x -> fp16
    const int idx = bid * 256 + t;
    float4 v = ((const float4*)x)[idx];
    f16x4 o;
    o[0] = (_Float16)v.x; o[1] = (_Float16)v.y; o[2] = (_Float16)v.z; o[3] = (_Float16)v.w;
    ((f16x4*)xb)[idx] = o;
    return;
  }
  bid -= 3072;
  if (bid < 1632) {  // tiled transpose f32 [K][N] -> fp16 [N][K]
    const float* in; _Float16* out; int K_, N_, bx, by;
    if (bid < 1152) {
      const int z = bid / 384, rem = bid % 384;
      in = (z == 0) ? Wq : (z == 1) ? Wk : Wv;
      out = wqkvt + (size_t)z * 512 * 768;
      K_ = 768; N_ = 512; bx = rem & 15; by = rem >> 4;
    } else if (bid < 1248) {
      const int rem = bid - 1152;
      in = Wrel; out = wrelt;
      K_ = 192; N_ = 512; bx = rem & 15; by = rem >> 4;
    } else {
      const int rem = bid - 1248;
      in = Wo; out = wot;
      K_ = 512; N_ = 768; bx = rem % 24; by = rem / 24;
    }
    const int k0 = by * 32, n0 = bx * 32;
    const int tr = t >> 3, tc = (t & 7) * 4;
    float4 v = *(const float4*)(in + (size_t)(k0 + tr) * N_ + n0 + tc);
    tile[tr][tc] = v.x; tile[tr][tc + 1] = v.y; tile[tr][tc + 2] = v.z; tile[tr][tc + 3] = v.w;
    __syncthreads();
    f16x4 o;
    o[0] = (_Float16)tile[tc][tr];
    o[1] = (_Float16)tile[tc + 1][tr];
    o[2] = (_Float16)tile[tc + 2][tr];
    o[3] = (_Float16)tile[tc + 3][tr];
    *(f16x4*)(out + (size_t)(n0 + tr) * K_ + k0 + tc) = o;
    return;
  }
  bid -= 1632;  // positional embedding: 8 rows / block
  const int lr = t >> 5, i = t & 31;
  const int r = bid * 8 + lr;
  _Float16* row = posb + (size_t)r * 192;
  if (r >= 4095) {
    row[i] = (_Float16)0.f; row[32 + i] = (_Float16)0.f; row[64 + i] = (_Float16)0.f;
    row[96 + i] = (_Float16)0.f; row[128 + i] = (_Float16)0.f; row[160 + i] = (_Float16)0.f;
    return;
  }
  const float dist = (float)(r - 2047);
  const float absd = fabsf(dist);
  const float sgn = (dist > 0.f) ? 1.f : ((dist < 0.f) ? -1.f : 0.f);
  const float e = 3.f + (float)i * (8.f / 31.f);
  const float expv = exp2f(-absd * exp2f(-e));
  const float cw = exp2f((float)(i + 1)) - 1.f;
  const float cm = (cw > absd) ? 1.f : 0.f;
  const float mean = 64.f * (float)(i + 1);
  const float conc = (mean / 32.f) * (mean / 32.f);
  const float rate = mean / 1024.f;
  const float lnrm = lgammaf(conc) - conc * logf(rate);
  const float lu = (conc - 1.f) * logf(absd) - rate * absd;
  float gv = expf(lu - lnrm) + 1e-8f;
  float mx = gv;
  mx = fmaxf(mx, __shfl_xor(mx, 1));
  mx = fmaxf(mx, __shfl_xor(mx, 2));
  mx = fmaxf(mx, __shfl_xor(mx, 4));
  mx = fmaxf(mx, __shfl_xor(mx, 8));
  mx = fmaxf(mx, __shfl_xor(mx, 16));
  gv /= mx;
  row[i] = (_Float16)expv;              row[32 + i] = (_Float16)cm;
  row[64 + i] = (_Float16)gv;           row[96 + i] = (_Float16)(sgn * expv);
  row[128 + i] = (_Float16)(sgn * cm);  row[160 + i] = (_Float16)(sgn * gv);
}

// ---------------- merged qkv + relk GEMM (one launch; independent halves overlap) -------
// bid < 768: qkv  C[4096][1536] = xb[4096][768] x wqkvt^T  (12 x 64 tiles of 64x128)
// bid >= 768: relk C[4096][512] = posb[4096][192] x wrelt^T (4 x 64 tiles)
__global__ __launch_bounds__(256, 4) void gemm_qkvrel(
    const _Float16* __restrict__ xb, const _Float16* __restrict__ wqkvt,
    const _Float16* __restrict__ posb, const _Float16* __restrict__ wrelt,
    _Float16* __restrict__ qc, _Float16* __restrict__ qp,
    _Float16* __restrict__ kbo, _Float16* __restrict__ vt,
    _Float16* __restrict__ relk,
    const float* __restrict__ bc, const float* __restrict__ bp) {
  __shared__ __align__(16) _Float16 As[2][64 * 32];
  __shared__ __align__(16) _Float16 Bs[2][128 * 32];
  const int tid = threadIdx.x;
  const int w = tid >> 6, lane = tid & 63, g = lane >> 4, m = lane & 15;
  const int wr = w >> 1, wc = w & 1;
  const int bid = blockIdx.x;
  const bool isrel = bid >= 768;
  const _Float16* A; const _Float16* Bt; int K, row0, c0;
  if (isrel) {
    const int tt = bid - 768;
    A = posb; Bt = wrelt; K = 192;
    c0 = (tt & 3) * 128; row0 = (tt >> 2) * 64;
  } else {
    A = xb; Bt = wqkvt; K = 768;
    c0 = (bid % 12) * 128; row0 = (bid / 12) * 64;
  }

  const int arow = tid >> 2, asl = tid & 3;
  const int axor = asl ^ ((arow >> 1) & 3);
  const char* Ag = (const char*)(A + (size_t)(row0 + arow) * K) + (axor << 4);
  const int adst = (arow << 6) + (asl << 4);
  const int brow = w * 32 + (lane >> 2);
  const int bxor = asl ^ ((brow >> 1) & 3);
  const char* Bg = (const char*)(Bt + (size_t)(c0 + brow) * K) + (bxor << 4);
  const size_t bstep = (size_t)16 * K * 2;
  const int bdst = (brow << 6) + (asl << 4);

  int aoff[2], boff[4];
#pragma unroll
  for (int i = 0; i < 2; ++i) {
    const int ar = wr * 32 + i * 16 + m;
    aoff[i] = (ar << 6) + ((g ^ ((ar >> 1) & 3)) << 4);
  }
#pragma unroll
  for (int i = 0; i < 4; ++i) {
    const int br = wc * 64 + i * 16 + m;
    boff[i] = (br << 6) + ((g ^ ((br >> 1) & 3)) << 4);
  }

#define STAGEG(buf, k0v)                                       \
  GL16(Ag + ((k0v) << 1), (char*)As[buf] + adst);              \
  GL16(Bg + ((k0v) << 1), (char*)Bs[buf] + bdst);              \
  GL16(Bg + bstep + ((k0v) << 1), (char*)Bs[buf] + bdst + 1024);

  f32x4 acc[2][4] = {};
  STAGEG(0, 0);
  __syncthreads();
  const int nk = K >> 5;
  for (int ks = 0; ks < nk; ++ks) {
    const int cur = ks & 1;
    if (ks + 1 < nk) { STAGEG(cur ^ 1, (ks + 1) << 5); }
    const char* ap = (const char*)As[cur];
    const char* bp_ = (const char*)Bs[cur];
    f16x8 af[2], bf[4];
#pragma unroll
    for (int i = 0; i < 2; ++i) af[i] = *(const f16x8*)(ap + aoff[i]);
#pragma unroll
    for (int i = 0; i < 4; ++i) bf[i] = *(const f16x8*)(bp_ + boff[i]);
#pragma unroll
    for (int mi = 0; mi < 2; ++mi)
#pragma unroll
      for (int ni = 0; ni < 4; ++ni)
        acc[mi][ni] = MFMA16(af[mi], bf[ni], acc[mi][ni]);
    __syncthreads();
  }
#undef STAGEG

  if (isrel) {
#pragma unroll
    for (int ni = 0; ni < 4; ++ni) {
      const int col = c0 + wc * 64 + ni * 16 + m;
      const int hh = col >> 6, dk = col & 63;
#pragma unroll
      for (int mi = 0; mi < 2; ++mi)
#pragma unroll
        for (int r = 0; r < 4; ++r) {
          const int row = row0 + wr * 32 + mi * 16 + g * 4 + r;
          relk[((size_t)hh * 4096 + row) * 64 + dk] = (_Float16)acc[mi][ni][r];
        }
    }
  } else {
    const int proj = c0 >> 9;
#pragma unroll
    for (int ni = 0; ni < 4; ++ni) {
      const int col = c0 + wc * 64 + ni * 16 + m;
      const int c = col & 511, hh = c >> 6, dk = c & 63;
      float b0f = 0.f, b1f = 0.f;
      if (proj == 0) { b0f = bc[c]; b1f = bp[c]; }
      if (proj == 2) {
#pragma unroll
        for (int mi = 0; mi < 2; ++mi) {
          const int rowb = row0 + wr * 32 + mi * 16 + g * 4;
          const int bb = rowb >> 11, n = rowb & 2047;
          f16x4 pk;
#pragma unroll
          for (int r = 0; r < 4; ++r) pk[r] = (_Float16)acc[mi][ni][r];
          *(f16x4*)(vt + ((size_t)(bb * 8 + hh) * 64 + dk) * 2048 + n) = pk;
        }
      } else {
#pragma unroll
        for (int mi = 0; mi < 2; ++mi)
#pragma unroll
          for (int r = 0; r < 4; ++r) {
            const int row = row0 + wr * 32 + mi * 16 + g * 4 + r;
            const int bb = row >> 11, n = row & 2047;
            const size_t ad = ((size_t)(bb * 8 + hh) * 2048 + n) * 64 + dk;
            const float v = acc[mi][ni][r];
            if (proj == 0) {
              const float vs = v * 0.125f;  // DIM_KEY^-0.5
              qc[ad] = (_Float16)(vs + b0f);
              qp[ad] = (_Float16)(vs + b1f);
            } else {
              kbo[ad] = (_Float16)v;
            }
          }
      }
    }
  }
}

// ---------------- out-projection GEMM: out[4096][768] = attnb[4096][512] x wot^T + bo ----
__global__ __launch_bounds__(256, 4) void gemm_out(
    const _Float16* __restrict__ A, const _Float16* __restrict__ Bt,
    const float* __restrict__ bias, float* __restrict__ outf) {
  __shared__ __align__(16) _Float16 As[2][64 * 32];
  __shared__ __align__(16) _Float16 Bs[2][128 * 32];
  const int tid = threadIdx.x;
  const int w = tid >> 6, lane = tid & 63, g = lane >> 4, m = lane & 15;
  const int wr = w >> 1, wc = w & 1;
  const int K = 512;
  const int row0 = blockIdx.y * 64;
  const int c0 = blockIdx.x * 128;

  const int arow = tid >> 2, asl = tid & 3;
  const int axor = asl ^ ((arow >> 1) & 3);
  const char* Ag = (const char*)(A + (size_t)(row0 + arow) * K) + (axor << 4);
  const int adst = (arow << 6) + (asl << 4);
  const int brow = w * 32 + (lane >> 2);
  const int bxor = asl ^ ((brow >> 1) & 3);
  const char* Bg = (const char*)(Bt + (size_t)(c0 + brow) * K) + (bxor << 4);
  const size_t bstep = (size_t)16 * K * 2;
  const int bdst = (brow << 6) + (asl << 4);

  int aoff[2], boff[4];
#pragma unroll
  for (int i = 0; i < 2; ++i) {
    const int ar = wr * 32 + i * 16 + m;
    aoff[i] = (ar << 6) + ((g ^ ((ar >> 1) & 3)) << 4);
  }
#pragma unroll
  for (int i = 0; i < 4; ++i) {
    const int br = wc * 64 + i * 16 + m;
    boff[i] = (br << 6) + ((g ^ ((br >> 1) & 3)) << 4);
  }

#define STAGEG(buf, k0v)                                       \
  GL16(Ag + ((k0v) << 1), (char*)As[buf] + adst);              \
  GL16(Bg + ((k0v) << 1), (char*)Bs[buf] + bdst);              \
  GL16(Bg + bstep + ((k0v) << 1), (char*)Bs[buf] + bdst + 1024);

  f32x4 acc[2][4] = {};
  STAGEG(0, 0);
  __syncthreads();
  const int nk = K >> 5;
  for (int ks = 0; ks < nk; ++ks) {
    const int cur = ks & 1;
    if (ks + 1 < nk) { STAGEG(cur ^ 1, (ks + 1) << 5); }
    const char* ap = (const char*)As[cur];
    const char* bp_ = (const char*)Bs[cur];
    f16x8 af[2], bf[4];
#pragma unroll
    for (int i = 0; i < 2; ++i) af[i] = *(const f16x8*)(ap + aoff[i]);
#pragma unroll
    for (int i = 0; i < 4; ++i) bf[i] = *(const f16x8*)(bp_ + boff[i]);
#pragma unroll
    for (int mi = 0; mi < 2; ++mi)
#pragma unroll
      for (int ni = 0; ni < 4; ++ni)
        acc[mi][ni] = MFMA16(af[mi], bf[ni], acc[mi][ni]);
    __syncthreads();
  }
#undef STAGEG

#pragma unroll
  for (int ni = 0; ni < 4; ++ni) {
    const int col = c0 + wc * 64 + ni * 16 + m;
    const float bv = bias[col];
#pragma unroll
    for (int mi = 0; mi < 2; ++mi)
#pragma unroll
      for (int r = 0; r < 4; ++r) {
        const int row = row0 + wr * 32 + mi * 16 + g * 4 + r;
        outf[(size_t)row * 768 + col] = acc[mi][ni][r] + bv;
      }
  }
}

// ---------------- fused rel-pos attention: V-direct, R-ring, 3 blocks/CU ----------------
// grid 512 x 256 thr. LDS: K dbuf 2x8K [0,16K) | R ring 3x8K [16K,40K) | P 4x2304 [40K,~49K)
// Per j-tile: K from LDS dbuf; rel band from 3-slot ring (stage only 64 new rows/tile);
// V fragments read direct from global (L1/L2 resident). Softmax: DPP max + defer-rescale
// (THR=8); sum via MFMA-ones. s_setprio(1) around MFMA clusters.
__global__ __launch_bounds__(256, 3) void attn_kernel(
    const _Float16* __restrict__ qc, const _Float16* __restrict__ qp,
    const _Float16* __restrict__ kb, const _Float16* __restrict__ vtb,
    const _Float16* __restrict__ relkb, _Float16* __restrict__ attnb) {
  __shared__ __align__(16) char lds[50176];
  const int tid = threadIdx.x;
  const int w = tid >> 6, lane = tid & 63, g = lane >> 4, m = lane & 15;
  const int L = blockIdx.x;
  const int h = L & 7;
  const int r2 = L >> 3;
  const int b = r2 >> 5, xt = r2 & 31;
  const int bh = b * 8 + h;
  const int i0b = xt << 6;
  const int i0 = i0b + w * 16;
  const int dR = 1984 - i0b;  // rel band origin; chunk c = rows [dR+64c, +64), c in [0,33)

  // staging geometry: 32 rows/pass, 8 slots of 16B per 128B row; source slot pre-swizzled
  const int srow = tid >> 3, ssl = tid & 7;
  const int sxr16 = (ssl ^ (srow & 7)) << 4;
  const int dst16 = (srow << 7) + (ssl << 4);
  const char* kgs = (const char*)kb + ((size_t)bh << 18) + sxr16;
  const char* rgs = (const char*)relkb + ((size_t)h << 19) + sxr16;

  char* Kb0 = lds;
  char* Kb1 = lds + 8192;
  char* Ring = lds + 16384;

#define STAGE_K(dstp, j0v)                                              \
  GL16(kgs + ((size_t)((j0v) + srow) << 7), (dstp) + dst16);            \
  GL16(kgs + ((size_t)((j0v) + srow + 32) << 7), (dstp) + dst16 + 4096);
#define STAGE_R(dstp, c)                                                       \
  GL16(rgs + ((size_t)(dR + ((c) << 6) + srow) << 7), (dstp) + dst16);         \
  GL16(rgs + ((size_t)(dR + ((c) << 6) + srow + 32) << 7), (dstp) + dst16 + 4096);

  // prologue: K tile 0 + rel chunks 0,1
  STAGE_K(Kb0, 0);
  STAGE_R(Ring, 0);
  STAGE_R(Ring + 8192, 1);

  const size_t qbase = ((size_t)bh * 2048 + i0 + m) * 64 + g * 8;
  f16x8 qcf0 = *(const f16x8*)(qc + qbase);
  f16x8 qcf1 = *(const f16x8*)(qc + qbase + 32);
  f16x8 qpf0 = *(const f16x8*)(qp + qbase);
  f16x8 qpf1 = *(const f16x8*)(qp + qbase + 32);

  f16x8 onesv;
#pragma unroll
  for (int i = 0; i < 8; ++i) onesv[i] = (_Float16)1.f;

  __syncthreads();

  f32x4 acc_o[4] = {};
  f32x4 acc_l = {};
  float m_run[4];
#pragma unroll
  for (int r = 0; r < 4; ++r) m_run[r] = -1e30f;

  const int sx = m & 7;
  const int fo0 = (g ^ sx) << 4;
  const int fo1 = ((4 | g) ^ sx) << 4;
  const int lb0 = 48 - (w << 4);  // rel band local row base for cf=0 (row = lb0+16cf+m)
  _Float16* Pl = (_Float16*)(lds + 40960 + w * 2304);  // per-wave [16][72]

  char* rsA = Ring;           // slot holding chunk jt
  char* rsB = Ring + 8192;    // chunk jt+1
  char* rsC = Ring + 16384;   // staging target: chunk jt+2

  for (int jt = 0; jt < 32; ++jt) {
    if (jt < 31) {
      char* kn = (jt & 1) ? Kb0 : Kb1;
      STAGE_K(kn, (jt + 1) << 6);
      STAGE_R(rsC, jt + 2);
    }
    const char* curK = (jt & 1) ? Kb1 : Kb0;
    // ---- content logits S_c [16 x 64] ----
    __builtin_amdgcn_s_setprio(1);
    f32x4 sc[4] = {};
#pragma unroll
    for (int cf = 0; cf < 4; ++cf) {
      const char* kp = curK + ((m + (cf << 4)) << 7);
      sc[cf] = MFMA16(qcf0, *(const f16x8*)(kp + fo0), sc[cf]);
      sc[cf] = MFMA16(qcf1, *(const f16x8*)(kp + fo1), sc[cf]);
    }
    // ---- rel logits band R [16 x 80] from ring (2 live slots) ----
    f32x4 rc[5] = {};
#pragma unroll
    for (int cf = 0; cf < 5; ++cf) {
      const int lb = lb0 + (cf << 4);                // [0, 112]
      const char* sp = (lb & 64) ? rsB : rsA;
      const char* rp = sp + (((lb & 63) + m) << 7);
      rc[cf] = MFMA16(qpf0, *(const f16x8*)(rp + fo0), rc[cf]);
      rc[cf] = MFMA16(qpf1, *(const f16x8*)(rp + fo1), rc[cf]);
    }
    __builtin_amdgcn_s_setprio(0);
    // ---- in-register shift gather + add ----
#pragma unroll
    for (int r = 0; r < 4; ++r) {
      const int lr = g * 4 + r;
      const int u = 15 + m - lr;
      const int src = (g << 4) | (u & 15);
      const bool hi = (m > lr);
      float sh0 = __shfl(rc[0][r], src);
      float sh1 = __shfl(rc[1][r], src);
      float sh2 = __shfl(rc[2][r], src);
      float sh3 = __shfl(rc[3][r], src);
      float sh4 = __shfl(rc[4][r], src);
      sc[0][r] += hi ? sh1 : sh0;
      sc[1][r] += hi ? sh2 : sh1;
      sc[2][r] += hi ? sh3 : sh2;
      sc[3][r] += hi ? sh4 : sh3;
    }
    // ---- online softmax: DPP max + defer-rescale (THR=8) ----
    float mx[4];
#pragma unroll
    for (int r = 0; r < 4; ++r) {
      float v = fmaxf(fmaxf(sc[0][r], sc[1][r]), fmaxf(sc[2][r], sc[3][r]));
      mx[r] = dpp_fmax16(v);
    }
    const bool need = (mx[0] > m_run[0] + 8.f) || (mx[1] > m_run[1] + 8.f) ||
                      (mx[2] > m_run[2] + 8.f) || (mx[3] > m_run[3] + 8.f);
    if (__any(need)) {
#pragma unroll
      for (int r = 0; r < 4; ++r) {
        const float mnew = fmaxf(m_run[r], mx[r]);
        const float corr = __expf(m_run[r] - mnew);
        m_run[r] = mnew;
#pragma unroll
        for (int cf = 0; cf < 4; ++cf) acc_o[cf][r] *= corr;
        acc_l[r] *= corr;
      }
    }
    float P[4][4];
#pragma unroll
    for (int r = 0; r < 4; ++r)
#pragma unroll
      for (int cf = 0; cf < 4; ++cf)
        P[cf][r] = __expf(sc[cf][r] - m_run[r]);
    // ---- P -> fp16 -> wave-private LDS (same-wave DS ordering, no barrier) ----
#pragma unroll
    for (int cf = 0; cf < 4; ++cf)
#pragma unroll
      for (int r = 0; r < 4; ++r)
        Pl[(g * 4 + r) * 72 + cf * 16 + m] = (_Float16)P[cf][r];
    // ---- PV + row-sum: acc_o += P.V (V direct from global) ; acc_l += P.1 ----
    const size_t vbase = ((size_t)bh * 64 + m) * 2048 + ((size_t)jt << 6) + g * 8;
    __builtin_amdgcn_s_setprio(1);
#pragma unroll
    for (int ks = 0; ks < 2; ++ks) {
      f16x8 pa = *(const f16x8*)((const char*)Pl + m * 144 + ks * 64 + (g << 4));
#pragma unroll
      for (int cf = 0; cf < 4; ++cf) {
        f16x8 vf = *(const f16x8*)(vtb + vbase + (size_t)cf * 32768 + ks * 32);
        acc_o[cf] = MFMA16(pa, vf, acc_o[cf]);
      }
      acc_l = MFMA16(pa, onesv, acc_l);
    }
    __builtin_amdgcn_s_setprio(0);
    __syncthreads();
    char* tmp = rsA; rsA = rsB; rsB = rsC; rsC = tmp;
  }
  // ---- epilogue ----
#pragma unroll
  for (int cf = 0; cf < 4; ++cf)
#pragma unroll
    for (int r = 0; r < 4; ++r) {
      const int i = i0 + g * 4 + r;
      const float o = acc_o[cf][r] / acc_l[r];
      attnb[((size_t)(b * 2048 + i)) * 512 + h * 64 + cf * 16 + m] = (_Float16)o;
    }
#undef STAGE_K
#undef STAGE_R
}

extern "C" void kernel_launch(void* const* d_in, const int* in_sizes, int n_in,
                              void* d_out, int out_size, void* d_ws, size_t ws_size,
                              hipStream_t stream) {
  (void)in_sizes; (void)n_in; (void)out_size; (void)ws_size;
  const float* x    = (const float*)d_in[0];
  const float* Wq   = (const float*)d_in[1];
  const float* Wk   = (const float*)d_in[2];
  const float* Wv   = (const float*)d_in[3];
  const float* Wrel = (const float*)d_in[4];
  const float* bc   = (const float*)d_in[5];  // rel_content_bias [8*64]
  const float* bp   = (const float*)d_in[6];  // rel_pos_bias [8*64]
  const float* Wo   = (const float*)d_in[7];
  const float* bo   = (const float*)d_in[8];
  float* out = (float*)d_out;

  char* ws = (char*)d_ws;
  size_t off = 0;
  auto alloc = [&](size_t bytes) -> void* {
    void* p = ws + off;
    off += (bytes + 255) & ~(size_t)255;
    return p;
  };
  _Float16* xb     = (_Float16*)alloc(4096ull * 768 * 2);    // x in fp16
  _Float16* wqkvt  = (_Float16*)alloc(1536ull * 768 * 2);    // [Wq;Wk;Wv]^T fp16
  _Float16* wrelt  = (_Float16*)alloc(512ull * 192 * 2);
  _Float16* wot    = (_Float16*)alloc(768ull * 512 * 2);
  _Float16* posb   = (_Float16*)alloc(4096ull * 192 * 2);    // positional features (row 4095 = 0)
  _Float16* qcb    = (_Float16*)alloc(16ull * 2048 * 64 * 2);   // (q*scale + bc)  [b][h][n][64]
  _Float16* qpb    = (_Float16*)alloc(16ull * 2048 * 64 * 2);   // (q*scale + bp)
  _Float16* kbb    = (_Float16*)alloc(16ull * 2048 * 64 * 2);   // k [b][h][n][64]
  _Float16* vtb    = (_Float16*)alloc(16ull * 64 * 2048 * 2);   // v^T [b][h][64][n]
  _Float16* relkb  = (_Float16*)alloc(8ull * 4096 * 64 * 2);    // rel_k [h][4096][64]
  _Float16* attnb  = (_Float16*)alloc(4096ull * 512 * 2);       // attention output fp16

  prep_kernel<<<5216, 256, 0, stream>>>(x, Wq, Wk, Wv, Wrel, Wo,
                                        xb, wqkvt, wrelt, wot, posb);

  gemm_qkvrel<<<1024, 256, 0, stream>>>(xb, wqkvt, posb, wrelt,
                                        qcb, qpb, kbb, vtb, relkb, bc, bp);

  attn_kernel<<<512, 256, 0, stream>>>(qcb, qpb, kbb, vtb, relkb, attnb);

  gemm_out<<<dim3(6, 64), 256, 0, stream>>>(attnb, wot, bo, out);
}

// Round 11
// 188.822 us; speedup vs baseline: 1.1672x; 1.1672x over previous
//
#include <hip/hip_runtime.h>
#include <hip/hip_bf16.h>
#include <math.h>

// Sizes (fixed): BATCH=2, SEQ=2048, DIM=768, HEADS=8, DK=DV=64, F=192, d_inner=512
// All internal compute in fp16 storage + fp32 MFMA accumulation.

typedef _Float16 f16x8 __attribute__((ext_vector_type(8)));
typedef _Float16 f16x4 __attribute__((ext_vector_type(4)));
typedef __fp16 fp16x2 __attribute__((ext_vector_type(2)));  // cvt_pkrtz return type
typedef float f32x4 __attribute__((ext_vector_type(4)));

#define MFMA16(a, b, c) __builtin_amdgcn_mfma_f32_16x16x32_f16((a), (b), (c), 0, 0, 0)

// async global->LDS, 16B per lane; dest must be (wave-uniform base + lane*16)
#define GL16(gp, lp)                                                       \
  __builtin_amdgcn_global_load_lds(                                        \
      (const __attribute__((address_space(1))) void*)(gp),                 \
      (__attribute__((address_space(3))) void*)(lp), 16, 0, 0)

// 16-lane max-reduce on the VALU pipe (DPP), zero DS-pipe ops.
__device__ __forceinline__ float dpp_fmax16(float x) {
  int v;
  v = __builtin_amdgcn_update_dpp(0, __float_as_int(x), 0xB1, 0xf, 0xf, true);
  x = fmaxf(x, __int_as_float(v));
  v = __builtin_amdgcn_update_dpp(0, __float_as_int(x), 0x4E, 0xf, 0xf, true);
  x = fmaxf(x, __int_as_float(v));
  v = __builtin_amdgcn_update_dpp(0, __float_as_int(x), 0x141, 0xf, 0xf, true);
  x = fmaxf(x, __int_as_float(v));
  v = __builtin_amdgcn_update_dpp(0, __float_as_int(x), 0x140, 0xf, 0xf, true);
  x = fmaxf(x, __int_as_float(v));
  return x;
}

// ---------------- fused prep: x->fp16 | 3 weight transposes | pos embed ----------------
__global__ __launch_bounds__(256) void prep_kernel(
    const float* __restrict__ x, const float* __restrict__ Wq,
    const float* __restrict__ Wk, const float* __restrict__ Wv,
    const float* __restrict__ Wrel, const float* __restrict__ Wo,
    _Float16* __restrict__ xb, _Float16* __restrict__ wqkvt,
    _Float16* __restrict__ wrelt, _Float16* __restrict__ wot,
    _Float16* __restrict__ posb) {
  __shared__ float tile[32][33];
  const int t = threadIdx.x;
  int bid = blockIdx.x;
  if (bid < 3072) {  // x -> fp16
    const int idx = bid * 256 + t;
    float4 v = ((const float4*)x)[idx];
    f16x4 o;
    o[0] = (_Float16)v.x; o[1] = (_Float16)v.y; o[2] = (_Float16)v.z; o[3] = (_Float16)v.w;
    ((f16x4*)xb)[idx] = o;
    return;
  }
  bid -= 3072;
  if (bid < 1632) {  // tiled transpose f32 [K][N] -> fp16 [N][K]
    const float* in; _Float16* out; int K_, N_, bx, by;
    if (bid < 1152) {
      const int z = bid / 384, rem = bid % 384;
      in = (z == 0) ? Wq : (z == 1) ? Wk : Wv;
      out = wqkvt + (size_t)z * 512 * 768;
      K_ = 768; N_ = 512; bx = rem & 15; by = rem >> 4;
    } else if (bid < 1248) {
      const int rem = bid - 1152;
      in = Wrel; out = wrelt;
      K_ = 192; N_ = 512; bx = rem & 15; by = rem >> 4;
    } else {
      const int rem = bid - 1248;
      in = Wo; out = wot;
      K_ = 512; N_ = 768; bx = rem % 24; by = rem / 24;
    }
    const int k0 = by * 32, n0 = bx * 32;
    const int tr = t >> 3, tc = (t & 7) * 4;
    float4 v = *(const float4*)(in + (size_t)(k0 + tr) * N_ + n0 + tc);
    tile[tr][tc] = v.x; tile[tr][tc + 1] = v.y; tile[tr][tc + 2] = v.z; tile[tr][tc + 3] = v.w;
    __syncthreads();
    f16x4 o;
    o[0] = (_Float16)tile[tc][tr];
    o[1] = (_Float16)tile[tc + 1][tr];
    o[2] = (_Float16)tile[tc + 2][tr];
    o[3] = (_Float16)tile[tc + 3][tr];
    *(f16x4*)(out + (size_t)(n0 + tr) * K_ + k0 + tc) = o;
    return;
  }
  bid -= 1632;  // positional embedding: 8 rows / block
  const int lr = t >> 5, i = t & 31;
  const int r = bid * 8 + lr;
  _Float16* row = posb + (size_t)r * 192;
  if (r >= 4095) {
    row[i] = (_Float16)0.f; row[32 + i] = (_Float16)0.f; row[64 + i] = (_Float16)0.f;
    row[96 + i] = (_Float16)0.f; row[128 + i] = (_Float16)0.f; row[160 + i] = (_Float16)0.f;
    return;
  }
  const float dist = (float)(r - 2047);
  const float absd = fabsf(dist);
  const float sgn = (dist > 0.f) ? 1.f : ((dist < 0.f) ? -1.f : 0.f);
  const float e = 3.f + (float)i * (8.f / 31.f);
  const float expv = exp2f(-absd * exp2f(-e));
  const float cw = exp2f((float)(i + 1)) - 1.f;
  const float cm = (cw > absd) ? 1.f : 0.f;
  const float mean = 64.f * (float)(i + 1);
  const float conc = (mean / 32.f) * (mean / 32.f);
  const float rate = mean / 1024.f;
  const float lnrm = lgammaf(conc) - conc * logf(rate);
  const float lu = (conc - 1.f) * logf(absd) - rate * absd;
  float gv = expf(lu - lnrm) + 1e-8f;
  float mx = gv;
  mx = fmaxf(mx, __shfl_xor(mx, 1));
  mx = fmaxf(mx, __shfl_xor(mx, 2));
  mx = fmaxf(mx, __shfl_xor(mx, 4));
  mx = fmaxf(mx, __shfl_xor(mx, 8));
  mx = fmaxf(mx, __shfl_xor(mx, 16));
  gv /= mx;
  row[i] = (_Float16)expv;              row[32 + i] = (_Float16)cm;
  row[64 + i] = (_Float16)gv;           row[96 + i] = (_Float16)(sgn * expv);
  row[128 + i] = (_Float16)(sgn * cm);  row[160 + i] = (_Float16)(sgn * gv);
}

// ---------------- merged qkv + relk GEMM (one launch; independent halves overlap) -------
__global__ __launch_bounds__(256, 4) void gemm_qkvrel(
    const _Float16* __restrict__ xb, const _Float16* __restrict__ wqkvt,
    const _Float16* __restrict__ posb, const _Float16* __restrict__ wrelt,
    _Float16* __restrict__ qc, _Float16* __restrict__ qp,
    _Float16* __restrict__ kbo, _Float16* __restrict__ vt,
    _Float16* __restrict__ relk,
    const float* __restrict__ bc, const float* __restrict__ bp) {
  __shared__ __align__(16) _Float16 As[2][64 * 32];
  __shared__ __align__(16) _Float16 Bs[2][128 * 32];
  const int tid = threadIdx.x;
  const int w = tid >> 6, lane = tid & 63, g = lane >> 4, m = lane & 15;
  const int wr = w >> 1, wc = w & 1;
  const int bid = blockIdx.x;
  const bool isrel = bid >= 768;
  const _Float16* A; const _Float16* Bt; int K, row0, c0;
  if (isrel) {
    const int tt = bid - 768;
    A = posb; Bt = wrelt; K = 192;
    c0 = (tt & 3) * 128; row0 = (tt >> 2) * 64;
  } else {
    A = xb; Bt = wqkvt; K = 768;
    c0 = (bid % 12) * 128; row0 = (bid / 12) * 64;
  }

  const int arow = tid >> 2, asl = tid & 3;
  const int axor = asl ^ ((arow >> 1) & 3);
  const char* Ag = (const char*)(A + (size_t)(row0 + arow) * K) + (axor << 4);
  const int adst = (arow << 6) + (asl << 4);
  const int brow = w * 32 + (lane >> 2);
  const int bxor = asl ^ ((brow >> 1) & 3);
  const char* Bg = (const char*)(Bt + (size_t)(c0 + brow) * K) + (bxor << 4);
  const size_t bstep = (size_t)16 * K * 2;
  const int bdst = (brow << 6) + (asl << 4);

  int aoff[2], boff[4];
#pragma unroll
  for (int i = 0; i < 2; ++i) {
    const int ar = wr * 32 + i * 16 + m;
    aoff[i] = (ar << 6) + ((g ^ ((ar >> 1) & 3)) << 4);
  }
#pragma unroll
  for (int i = 0; i < 4; ++i) {
    const int br = wc * 64 + i * 16 + m;
    boff[i] = (br << 6) + ((g ^ ((br >> 1) & 3)) << 4);
  }

#define STAGEG(buf, k0v)                                       \
  GL16(Ag + ((k0v) << 1), (char*)As[buf] + adst);              \
  GL16(Bg + ((k0v) << 1), (char*)Bs[buf] + bdst);              \
  GL16(Bg + bstep + ((k0v) << 1), (char*)Bs[buf] + bdst + 1024);

  f32x4 acc[2][4] = {};
  STAGEG(0, 0);
  __syncthreads();
  const int nk = K >> 5;
  for (int ks = 0; ks < nk; ++ks) {
    const int cur = ks & 1;
    if (ks + 1 < nk) { STAGEG(cur ^ 1, (ks + 1) << 5); }
    const char* ap = (const char*)As[cur];
    const char* bp_ = (const char*)Bs[cur];
    f16x8 af[2], bf[4];
#pragma unroll
    for (int i = 0; i < 2; ++i) af[i] = *(const f16x8*)(ap + aoff[i]);
#pragma unroll
    for (int i = 0; i < 4; ++i) bf[i] = *(const f16x8*)(bp_ + boff[i]);
#pragma unroll
    for (int mi = 0; mi < 2; ++mi)
#pragma unroll
      for (int ni = 0; ni < 4; ++ni)
        acc[mi][ni] = MFMA16(af[mi], bf[ni], acc[mi][ni]);
    __syncthreads();
  }
#undef STAGEG

  if (isrel) {
#pragma unroll
    for (int ni = 0; ni < 4; ++ni) {
      const int col = c0 + wc * 64 + ni * 16 + m;
      const int hh = col >> 6, dk = col & 63;
#pragma unroll
      for (int mi = 0; mi < 2; ++mi)
#pragma unroll
        for (int r = 0; r < 4; ++r) {
          const int row = row0 + wr * 32 + mi * 16 + g * 4 + r;
          relk[((size_t)hh * 4096 + row) * 64 + dk] = (_Float16)acc[mi][ni][r];
        }
    }
  } else {
    const int proj = c0 >> 9;
#pragma unroll
    for (int ni = 0; ni < 4; ++ni) {
      const int col = c0 + wc * 64 + ni * 16 + m;
      const int c = col & 511, hh = c >> 6, dk = c & 63;
      float b0f = 0.f, b1f = 0.f;
      if (proj == 0) { b0f = bc[c]; b1f = bp[c]; }
      if (proj == 2) {
#pragma unroll
        for (int mi = 0; mi < 2; ++mi) {
          const int rowb = row0 + wr * 32 + mi * 16 + g * 4;
          const int bb = rowb >> 11, n = rowb & 2047;
          f16x4 pk;
#pragma unroll
          for (int r = 0; r < 4; ++r) pk[r] = (_Float16)acc[mi][ni][r];
          *(f16x4*)(vt + ((size_t)(bb * 8 + hh) * 64 + dk) * 2048 + n) = pk;
        }
      } else {
#pragma unroll
        for (int mi = 0; mi < 2; ++mi)
#pragma unroll
          for (int r = 0; r < 4; ++r) {
            const int row = row0 + wr * 32 + mi * 16 + g * 4 + r;
            const int bb = row >> 11, n = row & 2047;
            const size_t ad = ((size_t)(bb * 8 + hh) * 2048 + n) * 64 + dk;
            const float v = acc[mi][ni][r];
            if (proj == 0) {
              const float vs = v * 0.125f;  // DIM_KEY^-0.5
              qc[ad] = (_Float16)(vs + b0f);
              qp[ad] = (_Float16)(vs + b1f);
            } else {
              kbo[ad] = (_Float16)v;
            }
          }
      }
    }
  }
}

// ---------------- out-projection GEMM: out[4096][768] = attnb[4096][512] x wot^T + bo ----
__global__ __launch_bounds__(256, 4) void gemm_out(
    const _Float16* __restrict__ A, const _Float16* __restrict__ Bt,
    const float* __restrict__ bias, float* __restrict__ outf) {
  __shared__ __align__(16) _Float16 As[2][64 * 32];
  __shared__ __align__(16) _Float16 Bs[2][128 * 32];
  const int tid = threadIdx.x;
  const int w = tid >> 6, lane = tid & 63, g = lane >> 4, m = lane & 15;
  const int wr = w >> 1, wc = w & 1;
  const int K = 512;
  const int row0 = blockIdx.y * 64;
  const int c0 = blockIdx.x * 128;

  const int arow = tid >> 2, asl = tid & 3;
  const int axor = asl ^ ((arow >> 1) & 3);
  const char* Ag = (const char*)(A + (size_t)(row0 + arow) * K) + (axor << 4);
  const int adst = (arow << 6) + (asl << 4);
  const int brow = w * 32 + (lane >> 2);
  const int bxor = asl ^ ((brow >> 1) & 3);
  const char* Bg = (const char*)(Bt + (size_t)(c0 + brow) * K) + (bxor << 4);
  const size_t bstep = (size_t)16 * K * 2;
  const int bdst = (brow << 6) + (asl << 4);

  int aoff[2], boff[4];
#pragma unroll
  for (int i = 0; i < 2; ++i) {
    const int ar = wr * 32 + i * 16 + m;
    aoff[i] = (ar << 6) + ((g ^ ((ar >> 1) & 3)) << 4);
  }
#pragma unroll
  for (int i = 0; i < 4; ++i) {
    const int br = wc * 64 + i * 16 + m;
    boff[i] = (br << 6) + ((g ^ ((br >> 1) & 3)) << 4);
  }

#define STAGEG(buf, k0v)                                       \
  GL16(Ag + ((k0v) << 1), (char*)As[buf] + adst);              \
  GL16(Bg + ((k0v) << 1), (char*)Bs[buf] + bdst);              \
  GL16(Bg + bstep + ((k0v) << 1), (char*)Bs[buf] + bdst + 1024);

  f32x4 acc[2][4] = {};
  STAGEG(0, 0);
  __syncthreads();
  const int nk = K >> 5;
  for (int ks = 0; ks < nk; ++ks) {
    const int cur = ks & 1;
    if (ks + 1 < nk) { STAGEG(cur ^ 1, (ks + 1) << 5); }
    const char* ap = (const char*)As[cur];
    const char* bp_ = (const char*)Bs[cur];
    f16x8 af[2], bf[4];
#pragma unroll
    for (int i = 0; i < 2; ++i) af[i] = *(const f16x8*)(ap + aoff[i]);
#pragma unroll
    for (int i = 0; i < 4; ++i) bf[i] = *(const f16x8*)(bp_ + boff[i]);
#pragma unroll
    for (int mi = 0; mi < 2; ++mi)
#pragma unroll
      for (int ni = 0; ni < 4; ++ni)
        acc[mi][ni] = MFMA16(af[mi], bf[ni], acc[mi][ni]);
    __syncthreads();
  }
#undef STAGEG

#pragma unroll
  for (int ni = 0; ni < 4; ++ni) {
    const int col = c0 + wc * 64 + ni * 16 + m;
    const float bv = bias[col];
#pragma unroll
    for (int mi = 0; mi < 2; ++mi)
#pragma unroll
      for (int r = 0; r < 4; ++r) {
        const int row = row0 + wr * 32 + mi * 16 + g * 4 + r;
        outf[(size_t)row * 768 + col] = acc[mi][ni][r] + bv;
      }
  }
}

// ---------------- fused rel-pos attention: K/V dbuf + R ring, packed gather ----------------
// grid 512 x 256 thr. LDS: K dbuf 2x8K | V dbuf 2x8K | R ring 3x8K | P 4x2304  (~65 KB)
// Per j-tile: K,V from LDS dbuf (gl_lds, pre-swizzled source); rel band from 3-slot ring
// (stage 64 new rows/tile). Gather: cvt_pkrtz pairs -> 3 shuffles/row (was 5).
// Softmax: DPP max + defer-rescale (THR=8); sum via MFMA-ones. setprio around MFMA.
__global__ __launch_bounds__(256, 2) void attn_kernel(
    const _Float16* __restrict__ qc, const _Float16* __restrict__ qp,
    const _Float16* __restrict__ kb, const _Float16* __restrict__ vtb,
    const _Float16* __restrict__ relkb, _Float16* __restrict__ attnb) {
  __shared__ __align__(16) char lds[66560];
  const int tid = threadIdx.x;
  const int w = tid >> 6, lane = tid & 63, g = lane >> 4, m = lane & 15;
  const int L = blockIdx.x;
  const int h = L & 7;
  const int r2 = L >> 3;
  const int b = r2 >> 5, xt = r2 & 31;
  const int bh = b * 8 + h;
  const int i0b = xt << 6;
  const int i0 = i0b + w * 16;
  const int dR = 1984 - i0b;  // rel band origin; chunk c = rows [dR+64c, +64), c in [0,33)

  // staging: 32 rows/pass, 8 slots of 16B per 128B row; source slot pre-swizzled
  const int srow = tid >> 3, ssl = tid & 7;
  const int sxr16 = (ssl ^ (srow & 7)) << 4;
  const int dst16 = (srow << 7) + (ssl << 4);
  const char* kgs = (const char*)kb + ((size_t)bh << 18) + sxr16;
  const char* vgs = (const char*)vtb + ((size_t)bh << 18) + ((size_t)srow << 12) + sxr16;
  const char* rgs = (const char*)relkb + ((size_t)h << 19) + sxr16;

  char* Kb0 = lds;
  char* Kb1 = lds + 8192;
  char* Vb0 = lds + 16384;
  char* Vb1 = lds + 24576;
  char* Ring = lds + 32768;

#define STAGE_K(dstp, j0v)                                              \
  GL16(kgs + ((size_t)((j0v) + srow) << 7), (dstp) + dst16);            \
  GL16(kgs + ((size_t)((j0v) + srow + 32) << 7), (dstp) + dst16 + 4096);
#define STAGE_V(dstp, j0v)                                              \
  GL16(vgs + ((j0v) << 1), (dstp) + dst16);                             \
  GL16(vgs + ((size_t)32 << 12) + ((j0v) << 1), (dstp) + dst16 + 4096);
#define STAGE_R(dstp, c)                                                       \
  GL16(rgs + ((size_t)(dR + ((c) << 6) + srow) << 7), (dstp) + dst16);         \
  GL16(rgs + ((size_t)(dR + ((c) << 6) + srow + 32) << 7), (dstp) + dst16 + 4096);

  // prologue: K/V tile 0, rel chunks 0,1
  STAGE_K(Kb0, 0);
  STAGE_V(Vb0, 0);
  STAGE_R(Ring, 0);
  STAGE_R(Ring + 8192, 1);

  const size_t qbase = ((size_t)bh * 2048 + i0 + m) * 64 + g * 8;
  f16x8 qcf0 = *(const f16x8*)(qc + qbase);
  f16x8 qcf1 = *(const f16x8*)(qc + qbase + 32);
  f16x8 qpf0 = *(const f16x8*)(qp + qbase);
  f16x8 qpf1 = *(const f16x8*)(qp + qbase + 32);

  f16x8 onesv;
#pragma unroll
  for (int i = 0; i < 8; ++i) onesv[i] = (_Float16)1.f;

  __syncthreads();

  f32x4 acc_o[4] = {};
  f32x4 acc_l = {};
  float m_run[4];
#pragma unroll
  for (int r = 0; r < 4; ++r) m_run[r] = -1e30f;

  const int sx = m & 7;
  const int fo0 = (g ^ sx) << 4;
  const int fo1 = ((4 | g) ^ sx) << 4;
  const int lb0 = 48 - (w << 4);  // rel band local row base for cf=0
  _Float16* Pl = (_Float16*)(lds + 57344 + w * 2304);  // per-wave [16][72]

  char* rsA = Ring;           // chunk jt
  char* rsB = Ring + 8192;    // chunk jt+1
  char* rsC = Ring + 16384;   // staging: chunk jt+2

  for (int jt = 0; jt < 32; ++jt) {
    if (jt < 31) {
      char* kn = (jt & 1) ? Kb0 : Kb1;
      char* vn = (jt & 1) ? Vb0 : Vb1;
      const int j0n = (jt + 1) << 6;
      STAGE_K(kn, j0n);
      STAGE_V(vn, j0n);
      STAGE_R(rsC, jt + 2);
    }
    const char* curK = (jt & 1) ? Kb1 : Kb0;
    const char* curV = (jt & 1) ? Vb1 : Vb0;
    // ---- content logits S_c [16 x 64] ----
    __builtin_amdgcn_s_setprio(1);
    f32x4 sc[4] = {};
#pragma unroll
    for (int cf = 0; cf < 4; ++cf) {
      const char* kp = curK + ((m + (cf << 4)) << 7);
      sc[cf] = MFMA16(qcf0, *(const f16x8*)(kp + fo0), sc[cf]);
      sc[cf] = MFMA16(qcf1, *(const f16x8*)(kp + fo1), sc[cf]);
    }
    // ---- rel logits band R [16 x 80] from ring (2 live slots) ----
    f32x4 rc[5] = {};
#pragma unroll
    for (int cf = 0; cf < 5; ++cf) {
      const int lb = lb0 + (cf << 4);                // [0, 112]
      const char* sp = (lb & 64) ? rsB : rsA;
      const char* rp = sp + (((lb & 63) + m) << 7);
      rc[cf] = MFMA16(qpf0, *(const f16x8*)(rp + fo0), rc[cf]);
      rc[cf] = MFMA16(qpf1, *(const f16x8*)(rp + fo1), rc[cf]);
    }
    __builtin_amdgcn_s_setprio(0);
    // ---- packed in-register shift gather: 3 shuffles/row (f16 pairs) ----
#pragma unroll
    for (int r = 0; r < 4; ++r) {
      const int lr = g * 4 + r;
      const int u = 15 + m - lr;
      const int src = (g << 4) | (u & 15);
      const bool hi = (m > lr);
      union { fp16x2 v; int i; __fp16 h[2]; } p01, p23, p4;
      p01.v = __builtin_amdgcn_cvt_pkrtz(rc[0][r], rc[1][r]);
      p23.v = __builtin_amdgcn_cvt_pkrtz(rc[2][r], rc[3][r]);
      p4.v  = __builtin_amdgcn_cvt_pkrtz(rc[4][r], rc[4][r]);
      p01.i = __shfl(p01.i, src);
      p23.i = __shfl(p23.i, src);
      p4.i  = __shfl(p4.i, src);
      sc[0][r] += (float)(hi ? p01.h[1] : p01.h[0]);
      sc[1][r] += (float)(hi ? p23.h[0] : p01.h[1]);
      sc[2][r] += (float)(hi ? p23.h[1] : p23.h[0]);
      sc[3][r] += (float)(hi ? p4.h[0] : p23.h[1]);
    }
    // ---- online softmax: DPP max + defer-rescale (THR=8) ----
    float mx[4];
#pragma unroll
    for (int r = 0; r < 4; ++r) {
      float v = fmaxf(fmaxf(sc[0][r], sc[1][r]), fmaxf(sc[2][r], sc[3][r]));
      mx[r] = dpp_fmax16(v);
    }
    const bool need = (mx[0] > m_run[0] + 8.f) || (mx[1] > m_run[1] + 8.f) ||
                      (mx[2] > m_run[2] + 8.f) || (mx[3] > m_run[3] + 8.f);
    if (__any(need)) {
#pragma unroll
      for (int r = 0; r < 4; ++r) {
        const float mnew = fmaxf(m_run[r], mx[r]);
        const float corr = __expf(m_run[r] - mnew);
        m_run[r] = mnew;
#pragma unroll
        for (int cf = 0; cf < 4; ++cf) acc_o[cf][r] *= corr;
        acc_l[r] *= corr;
      }
    }
    float P[4][4];
#pragma unroll
    for (int r = 0; r < 4; ++r)
#pragma unroll
      for (int cf = 0; cf < 4; ++cf)
        P[cf][r] = __expf(sc[cf][r] - m_run[r]);
    // ---- P -> fp16 -> wave-private LDS (same-wave DS ordering, no barrier) ----
#pragma unroll
    for (int cf = 0; cf < 4; ++cf)
#pragma unroll
      for (int r = 0; r < 4; ++r)
        Pl[(g * 4 + r) * 72 + cf * 16 + m] = (_Float16)P[cf][r];
    // ---- PV + row-sum: acc_o += P.V (V from LDS) ; acc_l += P.1 ----
    __builtin_amdgcn_s_setprio(1);
#pragma unroll
    for (int ks = 0; ks < 2; ++ks) {
      f16x8 pa = *(const f16x8*)((const char*)Pl + m * 144 + ks * 64 + (g << 4));
#pragma unroll
      for (int cf = 0; cf < 4; ++cf) {
        const char* vp = curV + ((m + (cf << 4)) << 7);
        acc_o[cf] = MFMA16(pa, *(const f16x8*)(vp + (ks ? fo1 : fo0)), acc_o[cf]);
      }
      acc_l = MFMA16(pa, onesv, acc_l);
    }
    __builtin_amdgcn_s_setprio(0);
    __syncthreads();
    char* tmp = rsA; rsA = rsB; rsB = rsC; rsC = tmp;
  }
  // ---- epilogue ----
#pragma unroll
  for (int cf = 0; cf < 4; ++cf)
#pragma unroll
    for (int r = 0; r < 4; ++r) {
      const int i = i0 + g * 4 + r;
      const float o = acc_o[cf][r] / acc_l[r];
      attnb[((size_t)(b * 2048 + i)) * 512 + h * 64 + cf * 16 + m] = (_Float16)o;
    }
#undef STAGE_K
#undef STAGE_V
#undef STAGE_R
}

extern "C" void kernel_launch(void* const* d_in, const int* in_sizes, int n_in,
                              void* d_out, int out_size, void* d_ws, size_t ws_size,
                              hipStream_t stream) {
  (void)in_sizes; (void)n_in; (void)out_size; (void)ws_size;
  const float* x    = (const float*)d_in[0];
  const float* Wq   = (const float*)d_in[1];
  const float* Wk   = (const float*)d_in[2];
  const float* Wv   = (const float*)d_in[3];
  const float* Wrel = (const float*)d_in[4];
  const float* bc   = (const float*)d_in[5];  // rel_content_bias [8*64]
  const float* bp   = (const float*)d_in[6];  // rel_pos_bias [8*64]
  const float* Wo   = (const float*)d_in[7];
  const float* bo   = (const float*)d_in[8];
  float* out = (float*)d_out;

  char* ws = (char*)d_ws;
  size_t off = 0;
  auto alloc = [&](size_t bytes) -> void* {
    void* p = ws + off;
    off += (bytes + 255) & ~(size_t)255;
    return p;
  };
  _Float16* xb     = (_Float16*)alloc(4096ull * 768 * 2);    // x in fp16
  _Float16* wqkvt  = (_Float16*)alloc(1536ull * 768 * 2);    // [Wq;Wk;Wv]^T fp16
  _Float16* wrelt  = (_Float16*)alloc(512ull * 192 * 2);
  _Float16* wot    = (_Float16*)alloc(768ull * 512 * 2);
  _Float16* posb   = (_Float16*)alloc(4096ull * 192 * 2);    // positional features (row 4095 = 0)
  _Float16* qcb    = (_Float16*)alloc(16ull * 2048 * 64 * 2);   // (q*scale + bc)  [b][h][n][64]
  _Float16* qpb    = (_Float16*)alloc(16ull * 2048 * 64 * 2);   // (q*scale + bp)
  _Float16* kbb    = (_Float16*)alloc(16ull * 2048 * 64 * 2);   // k [b][h][n][64]
  _Float16* vtb    = (_Float16*)alloc(16ull * 64 * 2048 * 2);   // v^T [b][h][64][n]
  _Float16* relkb  = (_Float16*)alloc(8ull * 4096 * 64 * 2);    // rel_k [h][4096][64]
  _Float16* attnb  = (_Float16*)alloc(4096ull * 512 * 2);       // attention output fp16

  prep_kernel<<<5216, 256, 0, stream>>>(x, Wq, Wk, Wv, Wrel, Wo,
                                        xb, wqkvt, wrelt, wot, posb);

  gemm_qkvrel<<<1024, 256, 0, stream>>>(xb, wqkvt, posb, wrelt,
                                        qcb, qpb, kbb, vtb, relkb, bc, bp);

  attn_kernel<<<512, 256, 0, stream>>>(qcb, qpb, kbb, vtb, relkb, attnb);

  gemm_out<<<dim3(6, 64), 256, 0, stream>>>(attnb, wot, bo, out);
}